// Round 1
// baseline (475.517 us; speedup 1.0000x reference)
//
#include <hip/hip_runtime.h>

#define B 128
#define C 2048
#define NENV 4
#define HW 196
#define HW4 49
#define EPSV 1e-5f
#define GRID 512          // persistent grid; co-resident: 2 blocks/CU guaranteed

typedef float f32x4 __attribute__((ext_vector_type(4)));

__device__ __forceinline__ float wave_sum(float v) {
    for (int o = 32; o; o >>= 1) v += __shfl_down(v, o, 64);
    return v;
}
__device__ __forceinline__ float wave_max(float v) {
    for (int o = 32; o; o >>= 1) v = fmaxf(v, __shfl_down(v, o, 64));
    return v;
}
__device__ __forceinline__ float wave_min(float v) {
    for (int o = 32; o; o >>= 1) v = fminf(v, __shfl_down(v, o, 64));
    return v;
}

// Batched 256-thread block reductions (bit-identical trees to prior rounds).
__device__ __forceinline__ float block_sum(float v, float* sred) {
    v = wave_sum(v);
    __syncthreads();
    if ((threadIdx.x & 63) == 0) sred[threadIdx.x >> 6] = v;
    __syncthreads();
    return (sred[0] + sred[1]) + (sred[2] + sred[3]);
}
__device__ __forceinline__ void block_sum2(float& a, float& b, float (*sr)[4]) {
    a = wave_sum(a); b = wave_sum(b);
    __syncthreads();
    const int w = threadIdx.x >> 6;
    if ((threadIdx.x & 63) == 0) { sr[0][w] = a; sr[1][w] = b; }
    __syncthreads();
    a = (sr[0][0] + sr[0][1]) + (sr[0][2] + sr[0][3]);
    b = (sr[1][0] + sr[1][1]) + (sr[1][2] + sr[1][3]);
}
__device__ __forceinline__ void block_sum4(float& a, float& b, float& c, float& d,
                                           float (*sr)[4]) {
    a = wave_sum(a); b = wave_sum(b); c = wave_sum(c); d = wave_sum(d);
    __syncthreads();
    const int w = threadIdx.x >> 6;
    if ((threadIdx.x & 63) == 0) { sr[0][w] = a; sr[1][w] = b; sr[2][w] = c; sr[3][w] = d; }
    __syncthreads();
    a = (sr[0][0] + sr[0][1]) + (sr[0][2] + sr[0][3]);
    b = (sr[1][0] + sr[1][1]) + (sr[1][2] + sr[1][3]);
    c = (sr[2][0] + sr[2][1]) + (sr[2][2] + sr[2][3]);
    d = (sr[3][0] + sr[3][1]) + (sr[3][2] + sr[3][3]);
}
__device__ __forceinline__ void block_max2(float& a, float& b, float (*sr)[4]) {
    a = wave_max(a); b = wave_max(b);
    __syncthreads();
    const int w = threadIdx.x >> 6;
    if ((threadIdx.x & 63) == 0) { sr[0][w] = a; sr[1][w] = b; }
    __syncthreads();
    a = fmaxf(fmaxf(sr[0][0], sr[0][1]), fmaxf(sr[0][2], sr[0][3]));
    b = fmaxf(fmaxf(sr[1][0], sr[1][1]), fmaxf(sr[1][2], sr[1][3]));
}
__device__ __forceinline__ void block_mm4(float& a, float& b, float& c, float& d,
                                          float (*sr)[4]) {
    a = wave_min(a); b = wave_max(b); c = wave_min(c); d = wave_max(d);
    __syncthreads();
    const int w = threadIdx.x >> 6;
    if ((threadIdx.x & 63) == 0) { sr[0][w] = a; sr[1][w] = b; sr[2][w] = c; sr[3][w] = d; }
    __syncthreads();
    a = fminf(fminf(sr[0][0], sr[0][1]), fminf(sr[0][2], sr[0][3]));
    b = fmaxf(fmaxf(sr[1][0], sr[1][1]), fmaxf(sr[1][2], sr[1][3]));
    c = fminf(fminf(sr[2][0], sr[2][1]), fminf(sr[2][2], sr[2][3]));
    d = fmaxf(fmaxf(sr[3][0], sr[3][1]), fmaxf(sr[3][2], sr[3][3]));
}
__device__ __forceinline__ void block_mm2(float& a, float& b, float (*sr)[4]) {
    a = wave_min(a); b = wave_max(b);
    __syncthreads();
    const int w = threadIdx.x >> 6;
    if ((threadIdx.x & 63) == 0) { sr[0][w] = a; sr[1][w] = b; }
    __syncthreads();
    a = fminf(fminf(sr[0][0], sr[0][1]), fminf(sr[0][2], sr[0][3]));
    b = fmaxf(fmaxf(sr[1][0], sr[1][1]), fmaxf(sr[1][2], sr[1][3]));
}

__device__ __forceinline__ float read_scalar01(const void* p) {
    float f = *(const float*)p;
    if (f > 1e-6f && f < 1.0f) return f;
    return (float)(*(const double*)p);
}

// Grid barrier (monotonic targets). Proven with 128 blocks; now 512 co-resident
// (LDS 50 KB -> <=3 blocks/CU fit; __launch_bounds__(256,2) caps VGPR at 256
//  -> >=2 blocks/CU -> capacity >= 512 = grid; no deadlock).
__device__ __forceinline__ void gridbar(int* bar, int target) {
    __syncthreads();
    if (threadIdx.x == 0) {
        __threadfence();
        __hip_atomic_fetch_add(bar, 1, __ATOMIC_RELEASE, __HIP_MEMORY_SCOPE_AGENT);
        while (__hip_atomic_load(bar, __ATOMIC_ACQUIRE, __HIP_MEMORY_SCOPE_AGENT) < target)
            __builtin_amdgcn_s_sleep(2);
        __threadfence();
    }
    __syncthreads();
}

// Tiny reset launch: the fused kernel cannot reset bar/cnt itself (any block
// could hit gridbar's atomicAdd before block 0's reset lands).
__global__ void k_init(int* __restrict__ cnt, int* __restrict__ bar) {
    cnt[0] = 0;
    bar[0] = 0;
}

// ---- Fully fused pipeline: avg -> stats -> row1 -> gram -> row2 -> apply ----
// One dispatch so (a) the two inter-kernel launch gaps disappear and (b) the
// kernel's FETCH/WRITE counters surface in the rocprof top-5 (the 3-kernel
// version was crowded out by the harness's 116 us fillBuffer resets).
// All arithmetic/summation trees are bit-identical to the passing 3-kernel
// version; only block->work mappings of avg/apply (element-independent) change.
__global__ __launch_bounds__(256, 2) void k_fused(const float* __restrict__ x,
        float* __restrict__ avg,
        float* __restrict__ tm, float* __restrict__ tv,
        float* __restrict__ em, float* __restrict__ ev,
        float* __restrict__ tota, float* __restrict__ enva,
        float* __restrict__ gram,
        const float* __restrict__ r,
        const void* __restrict__ ratiop, const void* __restrict__ rhop,
        float* __restrict__ mask01, int* __restrict__ cnt,
        int* __restrict__ bar,
        float* __restrict__ out) {
    __shared__ union {
        float cs[256 * HW4];                 // avg phase: 50176 B
        struct {                             // mid phases: ~13.4 KB
            double ps[16][16];
            double pss[16][16];
            unsigned skey[C];
            int hist[256];
            float sr[4][4];
            unsigned sprefix;
            int srem;
        } m;
    } u;
    const int tid = threadIdx.x, bid = blockIdx.x;

    // ---- phase 0: avg over H,W. 512 blocks x 2 chunks of 256 channels ----
    for (int ch = bid; ch < (B * C / 256); ch += GRID) {
        const f32x4* x4 = (const f32x4*)x + (size_t)ch * (256 * HW4);
        #pragma unroll
        for (int k = 0; k < HW4; ++k) {
            f32x4 v = x4[k * 256 + tid];
            u.cs[k * 256 + tid] = (v.x + v.y) + (v.z + v.w);
        }
        __syncthreads();
        // 64-slot binary tree with zero padding (identical tree to k_avg)
        float v[64];
        #pragma unroll
        for (int j = 0; j < HW4; ++j) v[j] = u.cs[tid * HW4 + j];
        #pragma unroll
        for (int j = HW4; j < 64; ++j) v[j] = 0.0f;
        #pragma unroll
        for (int o = 32; o; o >>= 1)
            #pragma unroll
            for (int l = 0; l < 32; ++l)
                if (l < o) v[l] += v[l + o];
        avg[ch * 256 + tid] = v[0] * (1.0f / 196.0f);
        __syncthreads();   // cs fully consumed before next chunk overwrites
    }
    gridbar(bar, GRID);

    // ---- phase 1: column stats, blocks 0..127 x 16 cols, one-pass fp64 ----
    if (bid < 128) {
        const int j = tid & 15;
        const int q = tid >> 4;
        const int c = bid * 16 + j;
        double s = 0.0, ss = 0.0;
        for (int i = 0; i < 8; ++i) {
            double a = (double)avg[(q * 8 + i) * C + c];
            s += a; ss += a * a;
        }
        u.m.ps[q][j] = s; u.m.pss[q][j] = ss;
        __syncthreads();
        if (tid < 64) {
            const int e = tid >> 4;
            double es = 0.0, ess = 0.0;
            for (int k = 0; k < 4; ++k) { es += u.m.ps[4 * e + k][j]; ess += u.m.pss[4 * e + k][j]; }
            double me = es * (1.0 / 32.0);
            em[e * C + c] = (float)me;
            ev[e * C + c] = (float)((ess - 32.0 * me * me) * (1.0 / 31.0));
        } else if (tid < 80) {
            const int jj = tid - 64;
            const int cc = bid * 16 + jj;
            double ts = 0.0, tss = 0.0;
            for (int k = 0; k < 16; ++k) { ts += u.m.ps[k][jj]; tss += u.m.pss[k][jj]; }
            double tmean = ts * (1.0 / 128.0);
            tm[cc] = (float)tmean;
            tv[cc] = (float)((tss - 128.0 * tmean * tmean) * (1.0 / 127.0));
        }
    }
    gridbar(bar, 2 * GRID);

    // ---- phase 2: per-row analytic grads + perturb + alignment (128 rows) ----
    if (bid < 128) {
        const int b = bid, e = b >> 5;
        const float rho = read_scalar01(rhop);
        float zt[8], ze[8];
        for (int j = 0; j < 8; ++j) {
            int c = tid + (j << 8);
            float a = avg[b * C + c];
            zt[j] = (a - tm[c]) / sqrtf(tv[c] + EPSV);
            ze[j] = (a - em[e * C + c]) / sqrtf(ev[e * C + c] + EPSV);
        }
        float mxt = -1e30f, mxe = -1e30f;
        for (int j = 0; j < 8; ++j) { mxt = fmaxf(mxt, zt[j]); mxe = fmaxf(mxe, ze[j]); }
        block_max2(mxt, mxe, u.m.sr);
        float st = 0.f, se = 0.f;
        for (int j = 0; j < 8; ++j) { st += expf(zt[j] - mxt); se += expf(ze[j] - mxe); }
        block_sum2(st, se, u.m.sr);
        const float lst = logf(st), lse = logf(se);
        float kl = 0.f;
        for (int j = 0; j < 8; ++j) {
            float lt = zt[j] - mxt - lst, le = ze[j] - mxe - lse;
            kl += expf(le) * (le - lt);
        }
        kl = block_sum(kl, u.m.sr[0]);
        float gmt[8], gme[8];
        float nmt = 0.f, nvt = 0.f, nme = 0.f, nve = 0.f;
        for (int j = 0; j < 8; ++j) {
            float lt = zt[j] - mxt - lst, le = ze[j] - mxe - lse;
            float pt = expf(lt), pe = expf(le);
            float g1 = (pt - pe) * (1.0f / 128.0f);
            float g2 = pe * ((le - lt) - kl) * (1.0f / 128.0f);
            gmt[j] = g1; gme[j] = g2;
            float gv = g1 * zt[j], ge = g2 * ze[j];
            nmt += g1 * g1; nvt += gv * gv;
            nme += g2 * g2; nve += ge * ge;
        }
        block_sum4(nmt, nvt, nme, nve, u.m.sr);
        const float dmt = sqrtf(sqrtf(nmt) + 1e-12f);
        const float dvt = sqrtf(sqrtf(nvt) + 1e-12f);
        const float dme = sqrtf(sqrtf(nme) + 1e-12f);
        const float dve = sqrtf(sqrtf(nve) + 1e-12f);
        for (int j = 0; j < 8; ++j) {
            int c = tid + (j << 8);
            float vt_ = 1.0f + (rho * (gmt[j] * zt[j])) / dvt;
            float mt_ = (rho * gmt[j]) / dmt;
            float ve_ = 1.0f + (rho * (gme[j] * ze[j])) / dve;
            float me_ = (rho * gme[j]) / dme;
            tota[b * C + c] = zt[j] * vt_ + mt_;
            enva[b * C + c] = ze[j] * ve_ + me_;
        }
    }
    gridbar(bar, 3 * GRID);

    // ---- phase 3: gram[c], blocks 0..127 x 16 cols, one-pass fp64 ----
    if (bid < 128) {
        const int j = tid & 15;
        const int q = tid >> 4;
        const int c = bid * 16 + j;
        double s = 0.0;
        for (int i = 0; i < 8; ++i) {
            int idx = (q * 8 + i) * C + c;
            s += ((double)tota[idx] + 1e-7) * ((double)enva[idx] + 1e-7);
        }
        u.m.ps[q][j] = s;
        __syncthreads();
        if (tid < 16) {
            double g = 0.0;
            for (int k = 0; k < 16; ++k) g += u.m.ps[k][tid];
            gram[bid * 16 + tid] = (float)g;
        }
    }
    gridbar(bar, 4 * GRID);

    // ---- phase 4: per-row scores -> key1 -> radix-select -> mask (128 rows) ----
    if (bid < 128) {
        const int b = bid;
        float t_[8], e_[8];
        for (int j = 0; j < 8; ++j) {
            int c = tid + (j << 8);
            float g = gram[c];
            t_[j] = tota[b * C + c] / g;
            e_[j] = enva[b * C + c] / g;
        }
        float tmin = 1e30f, tmax = -1e30f, emin = 1e30f, emax = -1e30f;
        for (int j = 0; j < 8; ++j) {
            tmin = fminf(tmin, t_[j]); tmax = fmaxf(tmax, t_[j]);
            emin = fminf(emin, e_[j]); emax = fmaxf(emax, e_[j]);
        }
        block_mm4(tmin, tmax, emin, emax, u.m.sr);
        const float tden = tmax - tmin, eden = emax - emin;
        float s0[8];
        float smin = 1e30f, smax = -1e30f;
        for (int j = 0; j < 8; ++j) {
            float tn = (t_[j] - tmin) / tden;
            float en = (e_[j] - emin) / eden;
            float d = tn - en;
            s0[j] = d * d;
            smin = fminf(smin, s0[j]); smax = fmaxf(smax, s0[j]);
        }
        block_mm2(smin, smax, u.m.sr);
        const float sden = smax - smin;
        float key[8];
        for (int j = 0; j < 8; ++j) {
            int c = tid + (j << 8);
            float sc = (s0[j] - smin) / sden;
            key[j] = powf(r[b * C + c], 1.0f / sc);
            u.m.skey[c] = __float_as_uint(key[j]);
        }
        const int kk = (int)(read_scalar01(ratiop) * (float)C);  // 614
        if (tid == 0) { u.m.sprefix = 0u; u.m.srem = kk; }
        __syncthreads();
        for (int pass = 0; pass < 4; ++pass) {
            const int d = 24 - 8 * pass;
            const unsigned pmask = (pass == 0) ? 0u : (0xFFFFFFFFu << (32 - 8 * pass));
            const unsigned pref = u.m.sprefix;
            const int krem = u.m.srem;
            u.m.hist[tid] = 0;
            __syncthreads();
            for (int j = 0; j < 8; ++j) {
                unsigned bits = u.m.skey[tid + (j << 8)];
                if ((bits & pmask) == pref) atomicAdd(&u.m.hist[(bits >> d) & 255], 1);
            }
            __syncthreads();
            if (tid < 64) {
                int s = (u.m.hist[tid * 4] + u.m.hist[tid * 4 + 1]) +
                        (u.m.hist[tid * 4 + 2] + u.m.hist[tid * 4 + 3]);
                int S = s;
                for (int o = 1; o < 64; o <<= 1) {
                    int t = __shfl_down(S, o, 64);
                    if (tid + o < 64) S += t;
                }
                unsigned long long bal = __ballot(S > krem);
                int hi = 63 - __clzll(bal);
                if (tid == hi) {
                    int cum = S - s;
                    for (int q = 3; q >= 0; --q) {
                        int h = u.m.hist[tid * 4 + q];
                        if (cum + h > krem) {
                            u.m.sprefix = pref | ((unsigned)(tid * 4 + q) << d);
                            u.m.srem = krem - cum;
                            break;
                        }
                        cum += h;
                    }
                }
            }
            __syncthreads();
        }
        const float thr = __uint_as_float(u.m.sprefix);
        float c8 = 0.f;
        for (int j = 0; j < 8; ++j) {
            int c = tid + (j << 8);
            float m = (key[j] > thr) ? 0.0f : 1.0f;
            mask01[b * C + c] = m;
            c8 += m;
        }
        c8 = block_sum(c8, u.m.sr[0]);
        if (tid == 0) atomicAdd(cnt, (int)c8);
    }
    gridbar(bar, 5 * GRID);

    // ---- phase 5: out = x * mask * scale; skip x-read for masked channels ----
    {
        const float s = 262144.0f / (float)cnt[0];
        const int base = bid * 256 + tid;
        #pragma unroll 4
        for (int k = 0; k < (B * C * HW4) / (GRID * 256); ++k) {   // 98 iters exactly
            int i = base + k * (GRID * 256);
            float m = mask01[i / HW4];
            f32x4 v = {0.f, 0.f, 0.f, 0.f};
            if (m != 0.0f) {
                v = *((const f32x4*)x + i);
                v *= (m * s);
            }
            __builtin_nontemporal_store(v, (f32x4*)out + i);
        }
    }
}

extern "C" void kernel_launch(void* const* d_in, const int* in_sizes, int n_in,
                              void* d_out, int out_size, void* d_ws, size_t ws_size,
                              hipStream_t stream) {
    const float* x = (const float*)d_in[0];
    const float* r = (const float*)d_in[1];
    const void* ratiop = d_in[2];
    const void* rhop = d_in[3];
    float* out = (float*)d_out;
    float* ws = (float*)d_ws;

    float* avg    = ws;                  // B*C
    float* tota   = avg    + B * C;      // B*C
    float* enva   = tota   + B * C;      // B*C
    float* mask01 = enva   + B * C;      // B*C
    float* tm     = mask01 + B * C;      // C
    float* tv     = tm + C;              // C
    float* em     = tv + C;              // NENV*C
    float* ev     = em + NENV * C;       // NENV*C
    float* gram   = ev + NENV * C;       // C
    int*   cnt    = (int*)(gram + C);    // 1
    int*   bar    = cnt + 1;             // 1

    k_init <<<dim3(1), dim3(1), 0, stream>>>(cnt, bar);
    k_fused<<<dim3(GRID), dim3(256), 0, stream>>>(x, avg, tm, tv, em, ev, tota, enva,
                                                  gram, r, ratiop, rhop, mask01, cnt,
                                                  bar, out);
}

// Round 2
// 316.662 us; speedup vs baseline: 1.5017x; 1.5017x over previous
//
#include <hip/hip_runtime.h>

#define B 128
#define C 2048
#define NENV 4
#define HW 196
#define HW4 49
#define EPSV 1e-5f
#define MIDREP 4   // instrumentation: repeat k_mid's phases to surface it in rocprof top-5

typedef float f32x4 __attribute__((ext_vector_type(4)));

__device__ __forceinline__ float wave_sum(float v) {
    for (int o = 32; o; o >>= 1) v += __shfl_down(v, o, 64);
    return v;
}
__device__ __forceinline__ float wave_max(float v) {
    for (int o = 32; o; o >>= 1) v = fmaxf(v, __shfl_down(v, o, 64));
    return v;
}
__device__ __forceinline__ float wave_min(float v) {
    for (int o = 32; o; o >>= 1) v = fminf(v, __shfl_down(v, o, 64));
    return v;
}

// Batched 256-thread block reductions. Each value keeps the EXACT per-value
// tree of rounds 2-7 (wave shuffle, lane0 -> LDS, (s0+s1)+(s2+s3)), but 2-4
// values share one barrier round. sr is __shared__ float[4][4].
__device__ __forceinline__ float block_sum(float v, float* sred) {
    v = wave_sum(v);
    __syncthreads();
    if ((threadIdx.x & 63) == 0) sred[threadIdx.x >> 6] = v;
    __syncthreads();
    return (sred[0] + sred[1]) + (sred[2] + sred[3]);
}
__device__ __forceinline__ void block_sum2(float& a, float& b, float (*sr)[4]) {
    a = wave_sum(a); b = wave_sum(b);
    __syncthreads();
    const int w = threadIdx.x >> 6;
    if ((threadIdx.x & 63) == 0) { sr[0][w] = a; sr[1][w] = b; }
    __syncthreads();
    a = (sr[0][0] + sr[0][1]) + (sr[0][2] + sr[0][3]);
    b = (sr[1][0] + sr[1][1]) + (sr[1][2] + sr[1][3]);
}
__device__ __forceinline__ void block_sum4(float& a, float& b, float& c, float& d,
                                           float (*sr)[4]) {
    a = wave_sum(a); b = wave_sum(b); c = wave_sum(c); d = wave_sum(d);
    __syncthreads();
    const int w = threadIdx.x >> 6;
    if ((threadIdx.x & 63) == 0) { sr[0][w] = a; sr[1][w] = b; sr[2][w] = c; sr[3][w] = d; }
    __syncthreads();
    a = (sr[0][0] + sr[0][1]) + (sr[0][2] + sr[0][3]);
    b = (sr[1][0] + sr[1][1]) + (sr[1][2] + sr[1][3]);
    c = (sr[2][0] + sr[2][1]) + (sr[2][2] + sr[2][3]);
    d = (sr[3][0] + sr[3][1]) + (sr[3][2] + sr[3][3]);
}
__device__ __forceinline__ void block_max2(float& a, float& b, float (*sr)[4]) {
    a = wave_max(a); b = wave_max(b);
    __syncthreads();
    const int w = threadIdx.x >> 6;
    if ((threadIdx.x & 63) == 0) { sr[0][w] = a; sr[1][w] = b; }
    __syncthreads();
    a = fmaxf(fmaxf(sr[0][0], sr[0][1]), fmaxf(sr[0][2], sr[0][3]));
    b = fmaxf(fmaxf(sr[1][0], sr[1][1]), fmaxf(sr[1][2], sr[1][3]));
}
// (min,max,min,max) in one round
__device__ __forceinline__ void block_mm4(float& a, float& b, float& c, float& d,
                                          float (*sr)[4]) {
    a = wave_min(a); b = wave_max(b); c = wave_min(c); d = wave_max(d);
    __syncthreads();
    const int w = threadIdx.x >> 6;
    if ((threadIdx.x & 63) == 0) { sr[0][w] = a; sr[1][w] = b; sr[2][w] = c; sr[3][w] = d; }
    __syncthreads();
    a = fminf(fminf(sr[0][0], sr[0][1]), fminf(sr[0][2], sr[0][3]));
    b = fmaxf(fmaxf(sr[1][0], sr[1][1]), fmaxf(sr[1][2], sr[1][3]));
    c = fminf(fminf(sr[2][0], sr[2][1]), fminf(sr[2][2], sr[2][3]));
    d = fmaxf(fmaxf(sr[3][0], sr[3][1]), fmaxf(sr[3][2], sr[3][3]));
}
__device__ __forceinline__ void block_mm2(float& a, float& b, float (*sr)[4]) {
    a = wave_min(a); b = wave_max(b);
    __syncthreads();
    const int w = threadIdx.x >> 6;
    if ((threadIdx.x & 63) == 0) { sr[0][w] = a; sr[1][w] = b; }
    __syncthreads();
    a = fminf(fminf(sr[0][0], sr[0][1]), fminf(sr[0][2], sr[0][3]));
    b = fmaxf(fmaxf(sr[1][0], sr[1][1]), fmaxf(sr[1][2], sr[1][3]));
}

// Python scalar may land as f32 or f64 single-element array; both ratio (0.3)
// and rho (0.05) are in (1e-6, 1). The f32 reinterpretation of a f64 in that
// range is far outside (1e-6, 1), so this sniff is unambiguous.
__device__ __forceinline__ float read_scalar01(const void* p) {
    float f = *(const float*)p;
    if (f > 1e-6f && f < 1.0f) return f;
    return (float)(*(const double*)p);
}

// Grid barrier for the 128-block k_mid (co-resident; proven rounds 2-7).
// Monotonic targets, so no counter reset between phases.
__device__ __forceinline__ void gridbar(int* bar, int target) {
    __syncthreads();
    if (threadIdx.x == 0) {
        __threadfence();
        __hip_atomic_fetch_add(bar, 1, __ATOMIC_RELEASE, __HIP_MEMORY_SCOPE_AGENT);
        while (__hip_atomic_load(bar, __ATOMIC_ACQUIRE, __HIP_MEMORY_SCOPE_AGENT) < target)
            __builtin_amdgcn_s_sleep(2);
        __threadfence();
    }
    __syncthreads();
}

// ---- K1: avg over H,W (round-5 version, bit-identical results; at HBM floor) ----
__global__ __launch_bounds__(256) void k_avg(const float* __restrict__ x,
                                             float* __restrict__ avg,
                                             int* __restrict__ cnt,
                                             int* __restrict__ bar) {
    __shared__ float cs[256 * HW4];     // 50176 B
    const int t = threadIdx.x;
    if (blockIdx.x == 0 && t == 0) { cnt[0] = 0; bar[0] = 0; }
    const f32x4* x4 = (const f32x4*)x + (size_t)blockIdx.x * (256 * HW4);
    #pragma unroll
    for (int k = 0; k < HW4; ++k) {
        f32x4 v = x4[k * 256 + t];
        cs[k * 256 + t] = (v.x + v.y) + (v.z + v.w);
    }
    __syncthreads();
    // 64-slot binary tree with zero padding == wave_sum over 49 active lanes
    float v[64];
    #pragma unroll
    for (int j = 0; j < HW4; ++j) v[j] = cs[t * HW4 + j];
    #pragma unroll
    for (int j = HW4; j < 64; ++j) v[j] = 0.0f;
    #pragma unroll
    for (int o = 32; o; o >>= 1)
        #pragma unroll
        for (int l = 0; l < 32; ++l)
            if (l < o) v[l] += v[l + o];
    avg[blockIdx.x * 256 + t] = v[0] * (1.0f / 196.0f);
}

// ---- K2 (fused middle): stats -> row1 -> gram -> row2, 128 blocks ----
// INSTRUMENTATION ROUND: phases repeated MIDREP times (idempotent; cnt add
// guarded to rep 0; barrier targets monotonic) so k_mid's duration/counters
// surface above the harness's ~116 us fill dispatches in the rocprof top-5.
// dur_us ~= baseline + (MIDREP-1) * T_mid.
__global__ __launch_bounds__(256) void k_mid(const float* __restrict__ avg,
        float* __restrict__ tm, float* __restrict__ tv,
        float* __restrict__ em, float* __restrict__ ev,
        float* __restrict__ tota, float* __restrict__ enva,
        float* __restrict__ gram,
        const float* __restrict__ r,
        const void* __restrict__ ratiop, const void* __restrict__ rhop,
        float* __restrict__ mask01, int* __restrict__ cnt,
        int* __restrict__ bar) {
    __shared__ double ps[16][16];
    __shared__ double pss[16][16];
    __shared__ unsigned skey[C];
    __shared__ int hist[256];
    __shared__ float sr[4][4];
    __shared__ unsigned sprefix;
    __shared__ int srem;
    const int tid = threadIdx.x, bid = blockIdx.x;
    int bt = 0;   // running gridbar target (monotonic across reps)

    for (int rep = 0; rep < MIDREP; ++rep) {

    // ---- phase 1: column stats, ALL 128 blocks x 16 cols, one-pass fp64 ----
    {
        const int j = tid & 15;          // col within block's 16
        const int q = tid >> 4;          // row octet 0..15 (8 rows each)
        const int c = bid * 16 + j;
        double s = 0.0, ss = 0.0;
        for (int i = 0; i < 8; ++i) {
            double a = (double)avg[(q * 8 + i) * C + c];
            s += a; ss += a * a;
        }
        ps[q][j] = s; pss[q][j] = ss;
        __syncthreads();
        if (tid < 64) {                  // env reducers: e = tid>>4, col j
            const int e = tid >> 4;
            double es = 0.0, ess = 0.0;
            for (int k = 0; k < 4; ++k) { es += ps[4 * e + k][j]; ess += pss[4 * e + k][j]; }
            double me = es * (1.0 / 32.0);
            em[e * C + c] = (float)me;
            ev[e * C + c] = (float)((ess - 32.0 * me * me) * (1.0 / 31.0));
        } else if (tid < 80) {           // total reducers: one col each
            const int jj = tid - 64;
            const int cc = bid * 16 + jj;
            double ts = 0.0, tss = 0.0;
            for (int k = 0; k < 16; ++k) { ts += ps[k][jj]; tss += pss[k][jj]; }
            double tmean = ts * (1.0 / 128.0);
            tm[cc] = (float)tmean;
            tv[cc] = (float)((tss - 128.0 * tmean * tmean) * (1.0 / 127.0));
        }
    }
    gridbar(bar, (bt += 128));

    // ---- phase 2: per-row analytic grads + perturb + alignment (all 128) ----
    {
        const int b = bid, e = b >> 5;
        const float rho = read_scalar01(rhop);
        float zt[8], ze[8];
        for (int j = 0; j < 8; ++j) {
            int c = tid + (j << 8);
            float a = avg[b * C + c];
            zt[j] = (a - tm[c]) / sqrtf(tv[c] + EPSV);
            ze[j] = (a - em[e * C + c]) / sqrtf(ev[e * C + c] + EPSV);
        }
        float mxt = -1e30f, mxe = -1e30f;
        for (int j = 0; j < 8; ++j) { mxt = fmaxf(mxt, zt[j]); mxe = fmaxf(mxe, ze[j]); }
        block_max2(mxt, mxe, sr);
        float st = 0.f, se = 0.f;
        for (int j = 0; j < 8; ++j) { st += expf(zt[j] - mxt); se += expf(ze[j] - mxe); }
        block_sum2(st, se, sr);
        const float lst = logf(st), lse = logf(se);
        float kl = 0.f;
        for (int j = 0; j < 8; ++j) {
            float lt = zt[j] - mxt - lst, le = ze[j] - mxe - lse;
            kl += expf(le) * (le - lt);
        }
        kl = block_sum(kl, sr[0]);
        float gmt[8], gme[8];
        float nmt = 0.f, nvt = 0.f, nme = 0.f, nve = 0.f;
        for (int j = 0; j < 8; ++j) {
            float lt = zt[j] - mxt - lst, le = ze[j] - mxe - lse;
            float pt = expf(lt), pe = expf(le);
            float g1 = (pt - pe) * (1.0f / 128.0f);
            float g2 = pe * ((le - lt) - kl) * (1.0f / 128.0f);
            gmt[j] = g1; gme[j] = g2;
            float gv = g1 * zt[j], ge = g2 * ze[j];
            nmt += g1 * g1; nvt += gv * gv;
            nme += g2 * g2; nve += ge * ge;
        }
        block_sum4(nmt, nvt, nme, nve, sr);
        // reference: p + rho*g / sqrt(norm(g) + 1e-12)  (sqrt of the L2 norm)
        const float dmt = sqrtf(sqrtf(nmt) + 1e-12f);
        const float dvt = sqrtf(sqrtf(nvt) + 1e-12f);
        const float dme = sqrtf(sqrtf(nme) + 1e-12f);
        const float dve = sqrtf(sqrtf(nve) + 1e-12f);
        for (int j = 0; j < 8; ++j) {
            int c = tid + (j << 8);
            float vt_ = 1.0f + (rho * (gmt[j] * zt[j])) / dvt;
            float mt_ = (rho * gmt[j]) / dmt;
            float ve_ = 1.0f + (rho * (gme[j] * ze[j])) / dve;
            float me_ = (rho * gme[j]) / dme;
            tota[b * C + c] = zt[j] * vt_ + mt_;
            enva[b * C + c] = ze[j] * ve_ + me_;
        }
    }
    gridbar(bar, (bt += 128));

    // ---- phase 3: gram[c], ALL 128 blocks x 16 cols, one-pass fp64 ----
    {
        const int j = tid & 15;
        const int q = tid >> 4;
        const int c = bid * 16 + j;
        double s = 0.0;
        for (int i = 0; i < 8; ++i) {
            int idx = (q * 8 + i) * C + c;
            s += ((double)tota[idx] + 1e-7) * ((double)enva[idx] + 1e-7);
        }
        ps[q][j] = s;
        __syncthreads();
        if (tid < 16) {
            double g = 0.0;
            for (int k = 0; k < 16; ++k) g += ps[k][tid];
            gram[bid * 16 + tid] = (float)g;
        }
    }
    gridbar(bar, (bt += 128));

    // ---- phase 4: per-row scores -> key1 -> radix-select -> mask (all 128) ----
    {
        const int b = bid;
        float t_[8], e_[8];
        for (int j = 0; j < 8; ++j) {
            int c = tid + (j << 8);
            float g = gram[c];
            t_[j] = tota[b * C + c] / g;
            e_[j] = enva[b * C + c] / g;
        }
        float tmin = 1e30f, tmax = -1e30f, emin = 1e30f, emax = -1e30f;
        for (int j = 0; j < 8; ++j) {
            tmin = fminf(tmin, t_[j]); tmax = fmaxf(tmax, t_[j]);
            emin = fminf(emin, e_[j]); emax = fmaxf(emax, e_[j]);
        }
        block_mm4(tmin, tmax, emin, emax, sr);
        const float tden = tmax - tmin, eden = emax - emin;
        float s0[8];
        float smin = 1e30f, smax = -1e30f;
        for (int j = 0; j < 8; ++j) {
            float tn = (t_[j] - tmin) / tden;
            float en = (e_[j] - emin) / eden;
            float d = tn - en;
            s0[j] = d * d;
            smin = fminf(smin, s0[j]); smax = fmaxf(smax, s0[j]);
        }
        block_mm2(smin, smax, sr);
        const float sden = smax - smin;
        float key[8];
        for (int j = 0; j < 8; ++j) {
            int c = tid + (j << 8);
            float sc = (s0[j] - smin) / sden;        // in [0,1]; 0 -> 1/sc=inf -> key 0
            key[j] = powf(r[b * C + c], 1.0f / sc);
            skey[c] = __float_as_uint(key[j]);       // keys >= 0: uint order == float order
        }
        const int kk = (int)(read_scalar01(ratiop) * (float)C);  // 614
        if (tid == 0) { sprefix = 0u; srem = kk; }
        __syncthreads();
        // 4-pass MSD radix select for the kk-th (0-based) largest key
        for (int pass = 0; pass < 4; ++pass) {
            const int d = 24 - 8 * pass;
            const unsigned pmask = (pass == 0) ? 0u : (0xFFFFFFFFu << (32 - 8 * pass));
            const unsigned pref = sprefix;
            const int krem = srem;
            hist[tid] = 0;
            __syncthreads();
            for (int j = 0; j < 8; ++j) {
                unsigned bits = skey[tid + (j << 8)];
                if ((bits & pmask) == pref) atomicAdd(&hist[(bits >> d) & 255], 1);
            }
            __syncthreads();
            if (tid < 64) {
                int s = (hist[tid * 4] + hist[tid * 4 + 1]) +
                        (hist[tid * 4 + 2] + hist[tid * 4 + 3]);
                int S = s;  // inclusive suffix sum (bins high->low as lane rises)
                for (int o = 1; o < 64; o <<= 1) {
                    int t = __shfl_down(S, o, 64);
                    if (tid + o < 64) S += t;
                }
                unsigned long long bal = __ballot(S > krem);
                int hi = 63 - __clzll(bal);          // highest lane whose suffix > krem
                if (tid == hi) {
                    int cum = S - s;                 // count in bins strictly above
                    for (int q = 3; q >= 0; --q) {
                        int h = hist[tid * 4 + q];
                        if (cum + h > krem) {
                            sprefix = pref | ((unsigned)(tid * 4 + q) << d);
                            srem = krem - cum;
                            break;
                        }
                        cum += h;
                    }
                }
            }
            __syncthreads();
        }
        const float thr = __uint_as_float(sprefix);
        float c8 = 0.f;
        for (int j = 0; j < 8; ++j) {
            int c = tid + (j << 8);
            float m = (key[j] > thr) ? 0.0f : 1.0f;  // keep low-key channels, ties kept
            mask01[b * C + c] = m;
            c8 += m;
        }
        c8 = block_sum(c8, sr[0]);
        if (tid == 0 && rep == 0) atomicAdd(cnt, (int)c8);
    }
    if (rep != MIDREP - 1) gridbar(bar, (bt += 128));

    }  // rep
}

// ---- K3: out = x * mask * scale; skip x-read for masked channels (at HBM floor) ----
__global__ __launch_bounds__(256) void k_apply(const float* __restrict__ x,
        const float* __restrict__ mask01, const int* __restrict__ cnt,
        float* __restrict__ out) {
    const float s = 262144.0f / (float)cnt[0];
    const int total4 = B * C * HW4;
    for (int i = blockIdx.x * 256 + threadIdx.x; i < total4; i += 2048 * 256) {
        float m = mask01[i / HW4];
        f32x4 v = {0.f, 0.f, 0.f, 0.f};
        if (m != 0.0f) {
            v = *((const f32x4*)x + i);
            v *= (m * s);
        }
        __builtin_nontemporal_store(v, (f32x4*)out + i);
    }
}

extern "C" void kernel_launch(void* const* d_in, const int* in_sizes, int n_in,
                              void* d_out, int out_size, void* d_ws, size_t ws_size,
                              hipStream_t stream) {
    const float* x = (const float*)d_in[0];
    const float* r = (const float*)d_in[1];
    const void* ratiop = d_in[2];
    const void* rhop = d_in[3];
    float* out = (float*)d_out;
    float* ws = (float*)d_ws;

    float* avg    = ws;                  // B*C
    float* tota   = avg    + B * C;      // B*C
    float* enva   = tota   + B * C;      // B*C
    float* mask01 = enva   + B * C;      // B*C
    float* tm     = mask01 + B * C;      // C
    float* tv     = tm + C;              // C
    float* em     = tv + C;              // NENV*C
    float* ev     = em + NENV * C;       // NENV*C
    float* gram   = ev + NENV * C;       // C
    int*   cnt    = (int*)(gram + C);    // 1
    int*   bar    = cnt + 1;             // 1

    k_avg  <<<dim3(B * C / 256), dim3(256), 0, stream>>>(x, avg, cnt, bar);
    k_mid  <<<dim3(128),  dim3(256), 0, stream>>>(avg, tm, tv, em, ev, tota, enva,
                                                  gram, r, ratiop, rhop, mask01, cnt, bar);
    k_apply<<<dim3(2048), dim3(256), 0, stream>>>(x, mask01, cnt, out);
}

// Round 3
// 113.454 us; speedup vs baseline: 4.1913x; 2.7911x over previous
//
#include <hip/hip_runtime.h>

#define B 128
#define C 2048
#define NENV 4
#define HW 196
#define HW4 49
#define EPSV 1e-5f

typedef float f32x4 __attribute__((ext_vector_type(4)));

__device__ __forceinline__ float wave_sum(float v) {
    for (int o = 32; o; o >>= 1) v += __shfl_down(v, o, 64);
    return v;
}
__device__ __forceinline__ float wave_max(float v) {
    for (int o = 32; o; o >>= 1) v = fmaxf(v, __shfl_down(v, o, 64));
    return v;
}
__device__ __forceinline__ float wave_min(float v) {
    for (int o = 32; o; o >>= 1) v = fminf(v, __shfl_down(v, o, 64));
    return v;
}

// Batched 256-thread block reductions (bit-identical trees to prior rounds).
__device__ __forceinline__ float block_sum(float v, float* sred) {
    v = wave_sum(v);
    __syncthreads();
    if ((threadIdx.x & 63) == 0) sred[threadIdx.x >> 6] = v;
    __syncthreads();
    return (sred[0] + sred[1]) + (sred[2] + sred[3]);
}
__device__ __forceinline__ void block_sum2(float& a, float& b, float (*sr)[4]) {
    a = wave_sum(a); b = wave_sum(b);
    __syncthreads();
    const int w = threadIdx.x >> 6;
    if ((threadIdx.x & 63) == 0) { sr[0][w] = a; sr[1][w] = b; }
    __syncthreads();
    a = (sr[0][0] + sr[0][1]) + (sr[0][2] + sr[0][3]);
    b = (sr[1][0] + sr[1][1]) + (sr[1][2] + sr[1][3]);
}
__device__ __forceinline__ void block_sum4(float& a, float& b, float& c, float& d,
                                           float (*sr)[4]) {
    a = wave_sum(a); b = wave_sum(b); c = wave_sum(c); d = wave_sum(d);
    __syncthreads();
    const int w = threadIdx.x >> 6;
    if ((threadIdx.x & 63) == 0) { sr[0][w] = a; sr[1][w] = b; sr[2][w] = c; sr[3][w] = d; }
    __syncthreads();
    a = (sr[0][0] + sr[0][1]) + (sr[0][2] + sr[0][3]);
    b = (sr[1][0] + sr[1][1]) + (sr[1][2] + sr[1][3]);
    c = (sr[2][0] + sr[2][1]) + (sr[2][2] + sr[2][3]);
    d = (sr[3][0] + sr[3][1]) + (sr[3][2] + sr[3][3]);
}
__device__ __forceinline__ void block_max2(float& a, float& b, float (*sr)[4]) {
    a = wave_max(a); b = wave_max(b);
    __syncthreads();
    const int w = threadIdx.x >> 6;
    if ((threadIdx.x & 63) == 0) { sr[0][w] = a; sr[1][w] = b; }
    __syncthreads();
    a = fmaxf(fmaxf(sr[0][0], sr[0][1]), fmaxf(sr[0][2], sr[0][3]));
    b = fmaxf(fmaxf(sr[1][0], sr[1][1]), fmaxf(sr[1][2], sr[1][3]));
}
// (min,max,min,max) in one round
__device__ __forceinline__ void block_mm4(float& a, float& b, float& c, float& d,
                                          float (*sr)[4]) {
    a = wave_min(a); b = wave_max(b); c = wave_min(c); d = wave_max(d);
    __syncthreads();
    const int w = threadIdx.x >> 6;
    if ((threadIdx.x & 63) == 0) { sr[0][w] = a; sr[1][w] = b; sr[2][w] = c; sr[3][w] = d; }
    __syncthreads();
    a = fminf(fminf(sr[0][0], sr[0][1]), fminf(sr[0][2], sr[0][3]));
    b = fmaxf(fmaxf(sr[1][0], sr[1][1]), fmaxf(sr[1][2], sr[1][3]));
    c = fminf(fminf(sr[2][0], sr[2][1]), fminf(sr[2][2], sr[2][3]));
    d = fmaxf(fmaxf(sr[3][0], sr[3][1]), fmaxf(sr[3][2], sr[3][3]));
}
__device__ __forceinline__ void block_mm2(float& a, float& b, float (*sr)[4]) {
    a = wave_min(a); b = wave_max(b);
    __syncthreads();
    const int w = threadIdx.x >> 6;
    if ((threadIdx.x & 63) == 0) { sr[0][w] = a; sr[1][w] = b; }
    __syncthreads();
    a = fminf(fminf(sr[0][0], sr[0][1]), fminf(sr[0][2], sr[0][3]));
    b = fmaxf(fmaxf(sr[1][0], sr[1][1]), fmaxf(sr[1][2], sr[1][3]));
}

// Python scalar may land as f32 or f64 single-element array; both ratio (0.3)
// and rho (0.05) are in (1e-6, 1). The f32 reinterpretation of a f64 in that
// range is far outside (1e-6, 1), so this sniff is unambiguous.
__device__ __forceinline__ float read_scalar01(const void* p) {
    float f = *(const float*)p;
    if (f > 1e-6f && f < 1.0f) return f;
    return (float)(*(const double*)p);
}

// ---- K1: avg over H,W (bit-identical tree; at HBM floor ~33 us) ----
__global__ __launch_bounds__(256) void k_avg(const float* __restrict__ x,
                                             float* __restrict__ avg,
                                             int* __restrict__ cnt) {
    __shared__ float cs[256 * HW4];     // 50176 B
    const int t = threadIdx.x;
    if (blockIdx.x == 0 && t == 0) cnt[0] = 0;
    const f32x4* x4 = (const f32x4*)x + (size_t)blockIdx.x * (256 * HW4);
    #pragma unroll
    for (int k = 0; k < HW4; ++k) {
        f32x4 v = x4[k * 256 + t];
        cs[k * 256 + t] = (v.x + v.y) + (v.z + v.w);
    }
    __syncthreads();
    // 64-slot binary tree with zero padding == wave_sum over 49 active lanes
    float v[64];
    #pragma unroll
    for (int j = 0; j < HW4; ++j) v[j] = cs[t * HW4 + j];
    #pragma unroll
    for (int j = HW4; j < 64; ++j) v[j] = 0.0f;
    #pragma unroll
    for (int o = 32; o; o >>= 1)
        #pragma unroll
        for (int l = 0; l < 32; ++l)
            if (l < o) v[l] += v[l + o];
    avg[blockIdx.x * 256 + t] = v[0] * (1.0f / 196.0f);
}

// ---- K2a: column stats (was k_mid phase 1). Kernel boundary = cheap barrier ----
// Round-2 instrumentation: gridbar costs ~14 us each (15 barriers / 240 us over
// 4 reps, HBM 1.3%, VALUBusy 6%); a dependent-dispatch boundary costs ~3 us.
__global__ __launch_bounds__(256) void k_stats(const float* __restrict__ avg,
        float* __restrict__ tm, float* __restrict__ tv,
        float* __restrict__ em, float* __restrict__ ev) {
    __shared__ double ps[16][16];
    __shared__ double pss[16][16];
    const int tid = threadIdx.x, bid = blockIdx.x;
    const int j = tid & 15;          // col within block's 16
    const int q = tid >> 4;          // row octet 0..15 (8 rows each)
    const int c = bid * 16 + j;
    double s = 0.0, ss = 0.0;
    for (int i = 0; i < 8; ++i) {
        double a = (double)avg[(q * 8 + i) * C + c];
        s += a; ss += a * a;
    }
    ps[q][j] = s; pss[q][j] = ss;
    __syncthreads();
    if (tid < 64) {                  // env reducers: e = tid>>4, col j
        const int e = tid >> 4;
        double es = 0.0, ess = 0.0;
        for (int k = 0; k < 4; ++k) { es += ps[4 * e + k][j]; ess += pss[4 * e + k][j]; }
        double me = es * (1.0 / 32.0);
        em[e * C + c] = (float)me;
        ev[e * C + c] = (float)((ess - 32.0 * me * me) * (1.0 / 31.0));
    } else if (tid < 80) {           // total reducers: one col each
        const int jj = tid - 64;
        const int cc = bid * 16 + jj;
        double ts = 0.0, tss = 0.0;
        for (int k = 0; k < 16; ++k) { ts += ps[k][jj]; tss += pss[k][jj]; }
        double tmean = ts * (1.0 / 128.0);
        tm[cc] = (float)tmean;
        tv[cc] = (float)((tss - 128.0 * tmean * tmean) * (1.0 / 127.0));
    }
}

// ---- K2b: per-row analytic grads + perturb + alignment (was phase 2) ----
__global__ __launch_bounds__(256) void k_row1(const float* __restrict__ avg,
        const float* __restrict__ tm, const float* __restrict__ tv,
        const float* __restrict__ em, const float* __restrict__ ev,
        float* __restrict__ tota, float* __restrict__ enva,
        const void* __restrict__ rhop) {
    __shared__ float sr[4][4];
    const int tid = threadIdx.x, b = blockIdx.x, e = b >> 5;
    const float rho = read_scalar01(rhop);
    float zt[8], ze[8];
    for (int j = 0; j < 8; ++j) {
        int c = tid + (j << 8);
        float a = avg[b * C + c];
        zt[j] = (a - tm[c]) / sqrtf(tv[c] + EPSV);
        ze[j] = (a - em[e * C + c]) / sqrtf(ev[e * C + c] + EPSV);
    }
    float mxt = -1e30f, mxe = -1e30f;
    for (int j = 0; j < 8; ++j) { mxt = fmaxf(mxt, zt[j]); mxe = fmaxf(mxe, ze[j]); }
    block_max2(mxt, mxe, sr);
    float st = 0.f, se = 0.f;
    for (int j = 0; j < 8; ++j) { st += expf(zt[j] - mxt); se += expf(ze[j] - mxe); }
    block_sum2(st, se, sr);
    const float lst = logf(st), lse = logf(se);
    float kl = 0.f;
    for (int j = 0; j < 8; ++j) {
        float lt = zt[j] - mxt - lst, le = ze[j] - mxe - lse;
        kl += expf(le) * (le - lt);
    }
    kl = block_sum(kl, sr[0]);
    float gmt[8], gme[8];
    float nmt = 0.f, nvt = 0.f, nme = 0.f, nve = 0.f;
    for (int j = 0; j < 8; ++j) {
        float lt = zt[j] - mxt - lst, le = ze[j] - mxe - lse;
        float pt = expf(lt), pe = expf(le);
        float g1 = (pt - pe) * (1.0f / 128.0f);
        float g2 = pe * ((le - lt) - kl) * (1.0f / 128.0f);
        gmt[j] = g1; gme[j] = g2;
        float gv = g1 * zt[j], ge = g2 * ze[j];
        nmt += g1 * g1; nvt += gv * gv;
        nme += g2 * g2; nve += ge * ge;
    }
    block_sum4(nmt, nvt, nme, nve, sr);
    // reference: p + rho*g / sqrt(norm(g) + 1e-12)  (sqrt of the L2 norm)
    const float dmt = sqrtf(sqrtf(nmt) + 1e-12f);
    const float dvt = sqrtf(sqrtf(nvt) + 1e-12f);
    const float dme = sqrtf(sqrtf(nme) + 1e-12f);
    const float dve = sqrtf(sqrtf(nve) + 1e-12f);
    for (int j = 0; j < 8; ++j) {
        int c = tid + (j << 8);
        float vt_ = 1.0f + (rho * (gmt[j] * zt[j])) / dvt;
        float mt_ = (rho * gmt[j]) / dmt;
        float ve_ = 1.0f + (rho * (gme[j] * ze[j])) / dve;
        float me_ = (rho * gme[j]) / dme;
        tota[b * C + c] = zt[j] * vt_ + mt_;
        enva[b * C + c] = ze[j] * ve_ + me_;
    }
}

// ---- K2c: gram[c] (was phase 3) ----
__global__ __launch_bounds__(256) void k_gram(const float* __restrict__ tota,
        const float* __restrict__ enva, float* __restrict__ gram) {
    __shared__ double ps[16][16];
    const int tid = threadIdx.x, bid = blockIdx.x;
    const int j = tid & 15;
    const int q = tid >> 4;
    const int c = bid * 16 + j;
    double s = 0.0;
    for (int i = 0; i < 8; ++i) {
        int idx = (q * 8 + i) * C + c;
        s += ((double)tota[idx] + 1e-7) * ((double)enva[idx] + 1e-7);
    }
    ps[q][j] = s;
    __syncthreads();
    if (tid < 16) {
        double g = 0.0;
        for (int k = 0; k < 16; ++k) g += ps[k][tid];
        gram[bid * 16 + tid] = (float)g;
    }
}

// ---- K2d: per-row scores -> key1 -> radix-select -> mask (was phase 4) ----
__global__ __launch_bounds__(256) void k_sel(const float* __restrict__ tota,
        const float* __restrict__ enva, const float* __restrict__ gram,
        const float* __restrict__ r,
        const void* __restrict__ ratiop,
        float* __restrict__ mask01, int* __restrict__ cnt) {
    __shared__ unsigned skey[C];
    __shared__ int hist[256];
    __shared__ float sr[4][4];
    __shared__ unsigned sprefix;
    __shared__ int srem;
    const int tid = threadIdx.x, b = blockIdx.x;
    float t_[8], e_[8];
    for (int j = 0; j < 8; ++j) {
        int c = tid + (j << 8);
        float g = gram[c];
        t_[j] = tota[b * C + c] / g;
        e_[j] = enva[b * C + c] / g;
    }
    float tmin = 1e30f, tmax = -1e30f, emin = 1e30f, emax = -1e30f;
    for (int j = 0; j < 8; ++j) {
        tmin = fminf(tmin, t_[j]); tmax = fmaxf(tmax, t_[j]);
        emin = fminf(emin, e_[j]); emax = fmaxf(emax, e_[j]);
    }
    block_mm4(tmin, tmax, emin, emax, sr);
    const float tden = tmax - tmin, eden = emax - emin;
    float s0[8];
    float smin = 1e30f, smax = -1e30f;
    for (int j = 0; j < 8; ++j) {
        float tn = (t_[j] - tmin) / tden;
        float en = (e_[j] - emin) / eden;
        float d = tn - en;
        s0[j] = d * d;
        smin = fminf(smin, s0[j]); smax = fmaxf(smax, s0[j]);
    }
    block_mm2(smin, smax, sr);
    const float sden = smax - smin;
    float key[8];
    for (int j = 0; j < 8; ++j) {
        int c = tid + (j << 8);
        float sc = (s0[j] - smin) / sden;        // in [0,1]; 0 -> 1/sc=inf -> key 0
        key[j] = powf(r[b * C + c], 1.0f / sc);
        skey[c] = __float_as_uint(key[j]);       // keys >= 0: uint order == float order
    }
    const int kk = (int)(read_scalar01(ratiop) * (float)C);  // 614
    if (tid == 0) { sprefix = 0u; srem = kk; }
    __syncthreads();
    // 4-pass MSD radix select for the kk-th (0-based) largest key
    for (int pass = 0; pass < 4; ++pass) {
        const int d = 24 - 8 * pass;
        const unsigned pmask = (pass == 0) ? 0u : (0xFFFFFFFFu << (32 - 8 * pass));
        const unsigned pref = sprefix;
        const int krem = srem;
        hist[tid] = 0;
        __syncthreads();
        for (int j = 0; j < 8; ++j) {
            unsigned bits = skey[tid + (j << 8)];
            if ((bits & pmask) == pref) atomicAdd(&hist[(bits >> d) & 255], 1);
        }
        __syncthreads();
        if (tid < 64) {
            int s = (hist[tid * 4] + hist[tid * 4 + 1]) +
                    (hist[tid * 4 + 2] + hist[tid * 4 + 3]);
            int S = s;  // inclusive suffix sum (bins high->low as lane rises)
            for (int o = 1; o < 64; o <<= 1) {
                int t = __shfl_down(S, o, 64);
                if (tid + o < 64) S += t;
            }
            unsigned long long bal = __ballot(S > krem);
            int hi = 63 - __clzll(bal);          // highest lane whose suffix > krem
            if (tid == hi) {
                int cum = S - s;                 // count in bins strictly above
                for (int q = 3; q >= 0; --q) {
                    int h = hist[tid * 4 + q];
                    if (cum + h > krem) {
                        sprefix = pref | ((unsigned)(tid * 4 + q) << d);
                        srem = krem - cum;
                        break;
                    }
                    cum += h;
                }
            }
        }
        __syncthreads();
    }
    const float thr = __uint_as_float(sprefix);
    float c8 = 0.f;
    for (int j = 0; j < 8; ++j) {
        int c = tid + (j << 8);
        float m = (key[j] > thr) ? 0.0f : 1.0f;  // keep low-key channels, ties kept
        mask01[b * C + c] = m;
        c8 += m;
    }
    c8 = block_sum(c8, sr[0]);
    if (tid == 0) atomicAdd(cnt, (int)c8);
}

// ---- K3: out = x * mask * scale; skip x-read for masked channels (near floor) ----
__global__ __launch_bounds__(256) void k_apply(const float* __restrict__ x,
        const float* __restrict__ mask01, const int* __restrict__ cnt,
        float* __restrict__ out) {
    const float s = 262144.0f / (float)cnt[0];
    const int total4 = B * C * HW4;
    for (int i = blockIdx.x * 256 + threadIdx.x; i < total4; i += 2048 * 256) {
        float m = mask01[i / HW4];
        f32x4 v = {0.f, 0.f, 0.f, 0.f};
        if (m != 0.0f) {
            v = *((const f32x4*)x + i);
            v *= (m * s);
        }
        __builtin_nontemporal_store(v, (f32x4*)out + i);
    }
}

extern "C" void kernel_launch(void* const* d_in, const int* in_sizes, int n_in,
                              void* d_out, int out_size, void* d_ws, size_t ws_size,
                              hipStream_t stream) {
    const float* x = (const float*)d_in[0];
    const float* r = (const float*)d_in[1];
    const void* ratiop = d_in[2];
    const void* rhop = d_in[3];
    float* out = (float*)d_out;
    float* ws = (float*)d_ws;

    float* avg    = ws;                  // B*C
    float* tota   = avg    + B * C;      // B*C
    float* enva   = tota   + B * C;      // B*C
    float* mask01 = enva   + B * C;      // B*C
    float* tm     = mask01 + B * C;      // C
    float* tv     = tm + C;              // C
    float* em     = tv + C;              // NENV*C
    float* ev     = em + NENV * C;       // NENV*C
    float* gram   = ev + NENV * C;       // C
    int*   cnt    = (int*)(gram + C);    // 1

    k_avg  <<<dim3(B * C / 256), dim3(256), 0, stream>>>(x, avg, cnt);
    k_stats<<<dim3(128), dim3(256), 0, stream>>>(avg, tm, tv, em, ev);
    k_row1 <<<dim3(128), dim3(256), 0, stream>>>(avg, tm, tv, em, ev, tota, enva, rhop);
    k_gram <<<dim3(128), dim3(256), 0, stream>>>(tota, enva, gram);
    k_sel  <<<dim3(128), dim3(256), 0, stream>>>(tota, enva, gram, r, ratiop, mask01, cnt);
    k_apply<<<dim3(2048), dim3(256), 0, stream>>>(x, mask01, cnt, out);
}